// Round 3
// 608.313 us; speedup vs baseline: 1.1260x; 1.1260x over previous
//
#include <hip/hip_runtime.h>

#define C 128

typedef __bf16 bf16_t;
typedef bf16_t bf16x8 __attribute__((ext_vector_type(8)));
typedef float f32x4 __attribute__((ext_vector_type(4)));

// ---- degree histogram (int) ----
__global__ void deg_kernel(const int* __restrict__ row, int* __restrict__ deg, int e) {
    int i = blockIdx.x * blockDim.x + threadIdx.x;
    if (i < e) atomicAdd(&deg[row[i]], 1);
}

// ---- W f32 -> bf16 row-major (fragment order == contiguous 8) ----
// Launched AFTER norm_kernel: Wb aliases the (then-dead) dis array.
__global__ void wcvt_kernel(const float* __restrict__ W, bf16_t* __restrict__ Wb) {
    int i = blockIdx.x * blockDim.x + threadIdx.x;
    if (i < C * C) Wb[i] = (bf16_t)W[i];
}

// ---- scan stage 1: per-block (1024 items) exclusive scan + block totals + dis ----
__global__ __launch_bounds__(256) void scan1_kernel(const int* __restrict__ deg,
                                                    float* __restrict__ dis,
                                                    int* __restrict__ offs,
                                                    int* __restrict__ partials, int n) {
    __shared__ int s[256];
    const int tid = threadIdx.x;
    const int base = blockIdx.x * 1024 + tid * 4;
    int v[4];
    #pragma unroll
    for (int j = 0; j < 4; ++j) v[j] = (base + j < n) ? deg[base + j] : 0;
    #pragma unroll
    for (int j = 0; j < 4; ++j)
        if (base + j < n) dis[base + j] = v[j] > 0 ? rsqrtf((float)v[j]) : 0.f;
    int tsum = v[0] + v[1] + v[2] + v[3];
    s[tid] = tsum;
    __syncthreads();
    for (int off = 1; off < 256; off <<= 1) {
        int t = (tid >= off) ? s[tid - off] : 0;
        __syncthreads();
        s[tid] += t;
        __syncthreads();
    }
    int excl = s[tid] - tsum;
    #pragma unroll
    for (int j = 0; j < 4; ++j) {
        if (base + j < n) offs[base + j] = excl;
        excl += v[j];
    }
    if (tid == 255) partials[blockIdx.x] = s[255];
}

// ---- scan stage 2: single block scans the block totals (exclusive, in place) ----
__global__ __launch_bounds__(1024) void scan2_kernel(int* __restrict__ partials, int nb) {
    __shared__ int s[1024];
    const int tid = threadIdx.x;
    int v = (tid < nb) ? partials[tid] : 0;
    s[tid] = v;
    __syncthreads();
    for (int off = 1; off < 1024; off <<= 1) {
        int t = (tid >= off) ? s[tid - off] : 0;
        __syncthreads();
        s[tid] += t;
        __syncthreads();
    }
    if (tid < nb) partials[tid] = s[tid] - v;
}

// ---- nrm[i] = dis[row[i]] * dis[col[i]]   (edge-indexed; reference later uses
//      nrm[col[e]] — nested indexing, do NOT factor) ----
__global__ void norm_kernel(const int* __restrict__ row, const int* __restrict__ col,
                            const float* __restrict__ dis, float* __restrict__ nrm, int e) {
    int i = blockIdx.x * blockDim.x + threadIdx.x;
    if (i < e) nrm[i] = dis[row[i]] * dis[col[i]];
}

// ---- bucket edges into CSR; pack {col, w} as one int2 (one 8B scattered store) ----
__global__ void bucket_kernel(const int* __restrict__ row, const int* __restrict__ col,
                              const int* __restrict__ offs, const int* __restrict__ partials,
                              const float* __restrict__ nrm, int* __restrict__ cursor,
                              int2* __restrict__ csr_cw, int e) {
    int i = blockIdx.x * blockDim.x + threadIdx.x;
    if (i < e) {
        int r = row[i];
        int c = col[i];
        int pos = atomicAdd(&cursor[r], 1);
        int idx = offs[r] + partials[r >> 10] + pos;
        csr_cw[idx] = make_int2(c, __float_as_int(nrm[c]));
    }
}

// ---- fused gather + linear ----
// out[r] = (sum_e w_e * x[c_e]) @ W^T + (sum_e w_e) * b,  w_e = nrm[col[e]].
// Wave owns 16 rows; lane (m,quad) accumulates Z[r0+m][kc*32+quad*8+j] directly
// in MFMA A-fragment layout. Edge loop 2-way unrolled for MLP; csr is a packed
// int2 (single 8B load); W pre-converted to bf16 (no per-wave cvt, half bytes);
// out stores nontemporal (don't evict x from L3).
__global__ __launch_bounds__(256, 4) void fused_kernel(
        const f32x4* __restrict__ x4, const int2* __restrict__ csr_cw,
        const int* __restrict__ offs, const int* __restrict__ partials,
        const int* __restrict__ deg, const bf16x8* __restrict__ Wb8,
        const float* __restrict__ bias, float* __restrict__ out, int n)
{
    const int lane = threadIdx.x & 63;
    const int wave = threadIdx.x >> 6;
    const int m    = lane & 15;
    const int quad = lane >> 4;
    const long r0  = ((long)blockIdx.x * 4 + wave) * 16;
    if (r0 >= n) return;
    const int  r  = (int)r0 + m;
    const bool rv = r < n;
    const int  d     = rv ? deg[r] : 0;
    const int  start = rv ? offs[r] + partials[r >> 10] : 0;

    f32x4 acc[8];
    #pragma unroll
    for (int i = 0; i < 8; ++i) acc[i] = (f32x4){0.f, 0.f, 0.f, 0.f};
    float sw = 0.f;

    int k = 0;
    for (; k + 2 <= d; k += 2) {
        const int2 cw0 = csr_cw[start + k];
        const int2 cw1 = csr_cw[start + k + 1];
        const float w0 = __int_as_float(cw0.y);
        const float w1 = __int_as_float(cw1.y);
        sw += w0 + w1;
        const f32x4* xr0 = x4 + (long)cw0.x * 32 + quad * 2;
        const f32x4* xr1 = x4 + (long)cw1.x * 32 + quad * 2;
        #pragma unroll
        for (int kc = 0; kc < 4; ++kc) {
            f32x4 u0 = xr0[kc * 8];
            f32x4 u1 = xr0[kc * 8 + 1];
            f32x4 v0 = xr1[kc * 8];
            f32x4 v1 = xr1[kc * 8 + 1];
            acc[kc * 2]     += w0 * u0;
            acc[kc * 2 + 1] += w0 * u1;
            acc[kc * 2]     += w1 * v0;
            acc[kc * 2 + 1] += w1 * v1;
        }
    }
    if (k < d) {
        const int2 cw = csr_cw[start + k];
        const float w = __int_as_float(cw.y);
        sw += w;
        const f32x4* xr = x4 + (long)cw.x * 32 + quad * 2;
        #pragma unroll
        for (int kc = 0; kc < 4; ++kc) {
            f32x4 u0 = xr[kc * 8];
            f32x4 u1 = xr[kc * 8 + 1];
            acc[kc * 2]     += w * u0;
            acc[kc * 2 + 1] += w * u1;
        }
    }

    // convert to MFMA A fragments (A[m][k = quad*8+j] per 32-wide K chunk)
    bf16x8 a[4];
    #pragma unroll
    for (int kc = 0; kc < 4; ++kc) {
        #pragma unroll
        for (int j = 0; j < 4; ++j) {
            a[kc][j]     = (bf16_t)acc[kc * 2][j];
            a[kc][j + 4] = (bf16_t)acc[kc * 2 + 1][j];
        }
    }

    // cnt for the 4 output rows this lane stores (C-layout: row = quad*4+v)
    float cv[4];
    #pragma unroll
    for (int v = 0; v < 4; ++v) cv[v] = __shfl(sw, quad * 4 + v);

    for (int t = 0; t < 8; ++t) {
        const int o = t * 16 + m;
        bf16x8 bf[4];
        #pragma unroll
        for (int kc = 0; kc < 4; ++kc)
            bf[kc] = Wb8[(long)o * 16 + kc * 4 + quad];   // W[o][kc*32+quad*8 + 0..7]
        f32x4 cacc = {0.f, 0.f, 0.f, 0.f};
        #pragma unroll
        for (int kc = 0; kc < 4; ++kc)
            cacc = __builtin_amdgcn_mfma_f32_16x16x32_bf16(a[kc], bf[kc], cacc, 0, 0, 0);
        const float bb = bias[o];
        #pragma unroll
        for (int v = 0; v < 4; ++v) {
            const long rr = r0 + quad * 4 + v;
            if (rr < n)
                __builtin_nontemporal_store(cacc[v] + cv[v] * bb, &out[rr * C + o]);
        }
    }
}

extern "C" void kernel_launch(void* const* d_in, const int* in_sizes, int n_in,
                              void* d_out, int out_size, void* d_ws, size_t ws_size,
                              hipStream_t stream) {
    const float* x  = (const float*)d_in[0];
    const int*   ei = (const int*)d_in[1];
    const float* W  = (const float*)d_in[2];
    const float* b  = (const float*)d_in[3];
    float* out = (float*)d_out;

    const int n = in_sizes[0] / C;   // nodes
    const int e = in_sizes[1] / 2;   // edges (== n)
    const int* row = ei;
    const int* col = ei + e;

    // Workspace layout: byte-identical footprint to the proven round-0 layout.
    // csr_cw (int2[e] = 8B*e) occupies exactly the old csr_col[e]+csr_w[e] 4MB
    // region; Wb (32KB) aliases dis[n], which is dead after norm_kernel.
    int*   deg_i    = (int*)d_ws;            // [n]
    int*   cursor   = deg_i + n;             // [n]  (memset with deg)
    int*   offs     = cursor + n;            // [n]
    int2*  csr_cw   = (int2*)(offs + n);     // [e] packed {col, w}  (8B-aligned: 3n*4 % 8 == 0)
    float* dis      = (float*)(csr_cw + e);  // [n]  (dead after norm_kernel)
    float* nrm      = dis + n;               // [e]
    int*   partials = (int*)(nrm + e);       // [<=1024]
    bf16_t* Wb      = (bf16_t*)dis;          // [C*C] bf16 = 32KB, aliases dis

    const int nb = (n + 1023) / 1024;        // 489 for n=500k (must be <=1024)

    hipMemsetAsync(deg_i, 0, (size_t)2 * n * sizeof(int), stream);  // deg + cursor

    deg_kernel<<<(e + 255) / 256, 256, 0, stream>>>(row, deg_i, e);
    scan1_kernel<<<nb, 256, 0, stream>>>(deg_i, dis, offs, partials, n);
    scan2_kernel<<<1, 1024, 0, stream>>>(partials, nb);
    norm_kernel<<<(e + 255) / 256, 256, 0, stream>>>(row, col, dis, nrm, e);
    wcvt_kernel<<<(C * C + 255) / 256, 256, 0, stream>>>(W, Wb);  // dis now dead
    bucket_kernel<<<(e + 255) / 256, 256, 0, stream>>>(row, col, offs, partials, nrm,
                                                       cursor, csr_cw, e);

    int blocks = (n + 63) / 64;
    fused_kernel<<<blocks, 256, 0, stream>>>(
        (const f32x4*)x, csr_cw, offs, partials, deg_i,
        (const bf16x8*)Wb, b, out, n);
}